// Round 1
// baseline (428.840 us; speedup 1.0000x reference)
//
#include <hip/hip_runtime.h>
#include <hip/hip_bf16.h>

#define BB   32
#define NN   2048
#define DIN  128
#define DOUT 256
#define DCTX 259

// ---- workspace layout (float-slot offsets) ----
#define OFF_TT   0u          // (tt no longer materialized) A aliases here
#define OFF_AB   0u          // A  bf16 [B][256][256] (dead before kF)
#define OFF_X1B  8388608u    // x1 bf16 [B][N][256] = 8388608 slots
#define OFF_WMB  16777216u   // WM bf16 [B][256 e][128 i] = 524288
#define OFF_WLB  17301504u   // W_layer bf16 [256 o][128 i] = 16384
#define OFF_WLTB 17317888u   // W_layer^T bf16 [128 i][256 o] = 16384
#define OFF_WTCB 17334272u   // W_tc bf16 [256 e][256 o] = 32768
#define OFF_G    17367040u
#define OFF_HB   17375232u
#define OFF_TB   17383424u
#define OFF_WKT  17391616u   // [256 c][256 o] fp32
#define OFF_WVT  17457152u
#define OFF_WGT  17522688u   // [259 c][256 o]
#define OFF_WHT  17588992u
#define OFF_STATS 17655296u  // [2048 n][2] fp32 atomics (s1,s2)
#define OFF_CNT   17659392u  // [32] arrival counters (uint)
// end 17659424 slots ≈ 70.6 MB

typedef short bf16x8 __attribute__((ext_vector_type(8)));
typedef float f32x4  __attribute__((ext_vector_type(4)));

static __device__ inline unsigned short f2bf(float f) {
    __hip_bfloat16 h = __float2bfloat16(f);
    return *(unsigned short*)&h;
}
static __device__ inline float bf2f(unsigned short u) {
    unsigned v = ((unsigned)u) << 16;
    float f;
    __builtin_memcpy(&f, &v, 4);
    return f;
}

// weight packing + stats zeroing. grid 45.
__global__ void kXW(const float* __restrict__ Wl, const float* __restrict__ Wtc,
                    const float* __restrict__ Wk, const float* __restrict__ Wv,
                    const float* __restrict__ Wg, const float* __restrict__ Whb,
                    float* __restrict__ ws) {
    unsigned bb = blockIdx.x, t = threadIdx.x;
    if (bb < 8u) {
        unsigned base = bb * 8192u;
        unsigned short* dst = (unsigned short*)(ws + OFF_WTCB);
#pragma unroll
        for (int j = 0; j < 32; j++) {
            unsigned i = base + (unsigned)j * 256u + t;
            dst[i] = f2bf(Wtc[i]);
        }
    } else if (bb == 8u) {
        unsigned short* dst = (unsigned short*)(ws + OFF_WLTB);   // [i][o]
        for (unsigned idx = t; idx < 32768u; idx += 256u) {
            unsigned i = idx >> 8, o = idx & 255u;
            dst[idx] = f2bf(Wl[o * 128u + i]);
        }
    } else if (bb == 9u) {
        unsigned short* dst = (unsigned short*)(ws + OFF_WLB);    // [o][i]
        for (unsigned idx = t; idx < 32768u; idx += 256u) dst[idx] = f2bf(Wl[idx]);
    } else if (bb == 44u) {
        // zero BN stats accumulators + arrival counters (re-zeroed every launch)
        for (unsigned i = t; i < 4128u; i += 256u) ws[OFF_STATS + i] = 0.f;
    } else {
        unsigned j = bb - 10u;
        const float* src; float* dst; unsigned C, c0;
        if (j < 8u)       { src = Wk;  dst = ws + OFF_WKT; C = 256; c0 = j * 32u; }
        else if (j < 16u) { src = Wv;  dst = ws + OFF_WVT; C = 256; c0 = (j - 8u) * 32u; }
        else if (j < 25u) { src = Wg;  dst = ws + OFF_WGT; C = 259; c0 = (j - 16u) * 32u; }
        else              { src = Whb; dst = ws + OFF_WHT; C = 259; c0 = (j - 25u) * 32u; }
        for (unsigned cc = c0; cc < c0 + 32u && cc < C; cc++)
            dst[cc * 256u + t] = src[t * C + cc];
    }
}

// Fused prep, 1024 threads: coalesced GEMVs + split softmax stats + A bf16. grid B.
__global__ __launch_bounds__(1024) void kP(const float* __restrict__ ctx,
                                           const float* __restrict__ bg,
                                           float* __restrict__ ws) {
    const int b = blockIdx.x, t = threadIdx.x;
    const int o = t & 255, q = t >> 8;
    __shared__ __align__(16) float cs[260];
    __shared__ __align__(16) float ks[256], vs[256], rms[256], ris[256];
    __shared__ float pm[1024], ps[1024];
    for (int i = t; i < DCTX; i += 1024) cs[i] = ctx[b * DCTX + i];
    __syncthreads();

    {
        const float* WT; int C;
        if (q == 0)      { WT = ws + OFF_WKT; C = 256; }
        else if (q == 1) { WT = ws + OFF_WVT; C = 256; }
        else if (q == 2) { WT = ws + OFF_WGT; C = DCTX; }
        else             { WT = ws + OFF_WHT; C = DCTX; }
        float s = 0.f;
#pragma unroll 8
        for (int c = 0; c < C; c++) s += WT[c * 256 + o] * cs[c];
        if (q == 0)      ks[o] = s;
        else if (q == 1) vs[o] = s;
        else if (q == 2) ws[OFF_G + b * DOUT + o] = 1.f / (1.f + __expf(-(s + bg[o])));
        else             ws[OFF_HB + b * DOUT + o] = s;
    }
    __syncthreads();

    const float ko = ks[o];
    const float4* vs4 = (const float4*)vs;
    float pmax = -1e30f;
#pragma unroll 4
    for (int j = q * 16; j < q * 16 + 16; j++) {
        float4 v = vs4[j];
        pmax = fmaxf(pmax, fmaxf(fmaxf(ko * v.x, ko * v.y), fmaxf(ko * v.z, ko * v.w)));
    }
    pm[q * 256 + o] = pmax;
    __syncthreads();
    float m = fmaxf(fmaxf(pm[o], pm[256 + o]), fmaxf(pm[512 + o], pm[768 + o]));
    float psum = 0.f;
#pragma unroll 4
    for (int j = q * 16; j < q * 16 + 16; j++) {
        float4 v = vs4[j];
        psum += __expf(ko * v.x - m) + __expf(ko * v.y - m)
              + __expf(ko * v.z - m) + __expf(ko * v.w - m);
    }
    ps[q * 256 + o] = psum;
    __syncthreads();
    float ri = 1.f / (ps[o] + ps[256 + o] + ps[512 + o] + ps[768 + o]);
    if (q == 0) { rms[o] = m; ris[o] = ri; }
    __syncthreads();

    const float ve = vs[o];
    float cp = 0.f;
#pragma unroll 4
    for (int o2 = q * 64; o2 < q * 64 + 64; o2++)
        cp += __expf(ks[o2] * ve - rms[o2]) * ris[o2];
    pm[q * 256 + o] = cp;
    __syncthreads();
    float ci = 1.f / (1e-9f + pm[o] + pm[256 + o] + pm[512 + o] + pm[768 + o]);
    unsigned short* Ab = (unsigned short*)(ws + OFF_AB) + (size_t)b * 65536u;
#pragma unroll 4
    for (int o2 = q * 64; o2 < q * 64 + 64; o2++) {
        float a = __expf(ks[o2] * ve - rms[o2]) * ris[o2] * ci;
        Ab[o2 * 256 + o] = f2bf(a);
    }
}

// Fused k4m+k5m: Mt (= Wtc - A-contraction) stays in LDS (XOR-swizzled, 16B granular),
// then WM = Mt @ Wl^T and tb GEMV. grid (2 e-halves, B), 512 threads (8 waves).
__global__ __launch_bounds__(512) void k45(const float* __restrict__ bl,
                                           const float* __restrict__ btc,
                                           float* __restrict__ ws) {
    const int t = threadIdx.x, wid = t >> 6, l = t & 63;
    const int b = blockIdx.y, et = blockIdx.x;
    const int lrow = l & 15, lk = l >> 4;
    __shared__ unsigned short Mt[128 * 256];   // 64 KB, swizzled: col ^ ((row&7)<<3)
    const unsigned short* Wtcb = (const unsigned short*)(ws + OFF_WTCB);

    // ---- phase A: Mt rows [et*128, et*128+128) ----
    {
        const unsigned short* Ab = (const unsigned short*)(ws + OFF_AB) + (size_t)b * 65536u;
        const int sub = wid >> 2, w2 = wid & 3;
        const int rbase = et * 128 + sub * 64 + (w2 & 1) * 32;
        const int colbase = (w2 >> 1) * 128;
        f32x4 acc[2][8];
#pragma unroll
        for (int i = 0; i < 2; i++)
#pragma unroll
            for (int c = 0; c < 8; c++) acc[i][c] = (f32x4){0.f, 0.f, 0.f, 0.f};
        const unsigned short* ar0 = Wtcb + (rbase + lrow) * 256;
#pragma unroll
        for (int kk = 0; kk < 8; kk++) {
            int ko = kk * 32 + lk * 8;
            bf16x8 a0 = *(const bf16x8*)(ar0 + ko);
            bf16x8 a1 = *(const bf16x8*)(ar0 + 16 * 256 + ko);
            bf16x8 bfr[8];
#pragma unroll
            for (int c = 0; c < 8; c++)
                bfr[c] = *(const bf16x8*)(Ab + (colbase + c * 16 + lrow) * 256 + ko);
#pragma unroll
            for (int c = 0; c < 8; c++) {
                acc[0][c] = __builtin_amdgcn_mfma_f32_16x16x32_bf16(a0, bfr[c], acc[0][c], 0, 0, 0);
                acc[1][c] = __builtin_amdgcn_mfma_f32_16x16x32_bf16(a1, bfr[c], acc[1][c], 0, 0, 0);
            }
        }
#pragma unroll
        for (int t2 = 0; t2 < 2; t2++)
#pragma unroll
            for (int c = 0; c < 8; c++)
#pragma unroll
                for (int r = 0; r < 4; r++) {
                    int grow = rbase + t2 * 16 + lk * 4 + r;
                    int col = colbase + c * 16 + lrow;
                    float idv = bf2f(Wtcb[grow * 256 + col]);
                    int rl = grow - et * 128;
                    Mt[rl * 256 + (col ^ ((rl & 7) << 3))] = f2bf(idv - acc[t2][c][r]);
                }
    }
    __syncthreads();
    // ---- phase B: WM rows = Mt @ Wl^T ----
    {
        const unsigned short* Wltb = (const unsigned short*)(ws + OFF_WLTB);
        const int rl0 = wid * 16;
        f32x4 acc[8];
#pragma unroll
        for (int c = 0; c < 8; c++) acc[c] = (f32x4){0.f, 0.f, 0.f, 0.f};
        const int arow = rl0 + lrow;
        const int asw = (arow & 7) << 3;
#pragma unroll
        for (int kk = 0; kk < 8; kk++) {
            int ko = kk * 32 + lk * 8;
            bf16x8 a0 = *(const bf16x8*)(Mt + arow * 256 + (ko ^ asw));
            bf16x8 bfr[8];
#pragma unroll
            for (int c = 0; c < 8; c++)
                bfr[c] = *(const bf16x8*)(Wltb + (c * 16 + lrow) * 256 + ko);
#pragma unroll
            for (int c = 0; c < 8; c++)
                acc[c] = __builtin_amdgcn_mfma_f32_16x16x32_bf16(a0, bfr[c], acc[c], 0, 0, 0);
        }
        unsigned short* WMBp = (unsigned short*)(ws + OFF_WMB) + (size_t)b * 32768u;
#pragma unroll
        for (int c = 0; c < 8; c++)
#pragma unroll
            for (int r = 0; r < 4; r++) {
                int row = et * 128 + rl0 + lk * 4 + r;
                int col = c * 16 + lrow;
                WMBp[row * 128 + col] = f2bf(acc[c][r]);
            }
    }
    // ---- tb bias GEMV from LDS Mt ----
    if (t < 128) {
        const int rl = t;
        const int sw = (rl & 7) << 3;
        float s = 0.f;
#pragma unroll 4
        for (int j = 0; j < 32; j++) {
            bf16x8 ch = *(const bf16x8*)(Mt + rl * 256 + ((j * 8) ^ sw));
#pragma unroll
            for (int u = 0; u < 8; u++) s += bl[j * 8 + u] * bf2f((unsigned short)ch[u]);
        }
        ws[OFF_TB + b * DOUT + et * 128 + rl] = s + btc[et * 128 + rl];
    }
}

// Fused dual-GEMM + BN stats + epilogue. tt stays in registers across a per-n-tile
// software barrier (stats via fp32 atomics, arrival counter per n-tile).
// __launch_bounds__(256,4): VGPR<=128, LDS 19.5KB -> 4 blocks/CU guaranteed ->
// all 1024 blocks co-resident -> spin barrier cannot deadlock. grid (32 nt, B).
#define LDP 136
__global__ __launch_bounds__(256, 4) void kF(const float* __restrict__ x,
                                             const float* __restrict__ bl,
                                             const float* __restrict__ gamma,
                                             const float* __restrict__ beta,
                                             float* __restrict__ out,
                                             float* __restrict__ ws) {
    const int t = threadIdx.x;
    const int wid = t >> 6, l = t & 63;
    const int b = blockIdx.y;
    const int nt = blockIdx.x;
    const int n0 = nt * 64;
    const int lrow = l & 15, lk = l >> 4;
    __shared__ unsigned short xs[64 * LDP];
    __shared__ float sp1[4][64], sp2[4][64];
    __shared__ float scs[64], shs[64];

    // stage x tile (64 rows x 128 k) fp32 -> bf16 LDS, coalesced 16B loads
    const float4* xg = (const float4*)(x + (size_t)(b * NN + n0) * DIN);
#pragma unroll
    for (int it = 0; it < 8; it++) {
        int idx = it * 256 + t;
        int row = idx >> 5, kq = idx & 31;
        float4 v = xg[idx];
        ushort4 u;
        u.x = f2bf(v.x); u.y = f2bf(v.y); u.z = f2bf(v.z); u.w = f2bf(v.w);
        *(ushort4*)(xs + row * LDP + kq * 4) = u;
    }
    __syncthreads();

    const int colbase = wid * 64;
    unsigned short* x1p = (unsigned short*)(ws + OFF_X1B);

    // ---- pass 0: x1 = x @ Wl^T + bl -> global bf16 (re-read L2-hot in epilogue) ----
    {
        const unsigned short* wb = (const unsigned short*)(ws + OFF_WLB);
        f32x4 acc0[4][4];
#pragma unroll
        for (int rt = 0; rt < 4; rt++)
#pragma unroll
            for (int ct = 0; ct < 4; ct++) acc0[rt][ct] = (f32x4){0.f, 0.f, 0.f, 0.f};
#pragma unroll
        for (int kk = 0; kk < 4; kk++) {
            int ko = kk * 32 + lk * 8;
            bf16x8 a[4];
#pragma unroll
            for (int rt = 0; rt < 4; rt++)
                a[rt] = *(const bf16x8*)(xs + (rt * 16 + lrow) * LDP + ko);
            bf16x8 bf[4];
#pragma unroll
            for (int ct = 0; ct < 4; ct++)
                bf[ct] = *(const bf16x8*)(wb + (size_t)(colbase + ct * 16 + lrow) * DIN + ko);
#pragma unroll
            for (int rt = 0; rt < 4; rt++)
#pragma unroll
                for (int ct = 0; ct < 4; ct++)
                    acc0[rt][ct] = __builtin_amdgcn_mfma_f32_16x16x32_bf16(a[rt], bf[ct], acc0[rt][ct], 0, 0, 0);
        }
#pragma unroll
        for (int ct = 0; ct < 4; ct++) {
            float bv = bl[colbase + ct * 16 + lrow];
#pragma unroll
            for (int rt = 0; rt < 4; rt++)
#pragma unroll
                for (int r = 0; r < 4; r++) {
                    int row = n0 + rt * 16 + lk * 4 + r;
                    int col = colbase + ct * 16 + lrow;
                    x1p[(size_t)((b * NN + row) * DOUT) + col] = f2bf(acc0[rt][ct][r] + bv);
                }
        }
    }

    // ---- pass 1: tt = x @ WM^T + tb -> REGISTERS (bias folded, never hits global) ----
    f32x4 acc[4][4];
#pragma unroll
    for (int rt = 0; rt < 4; rt++)
#pragma unroll
        for (int ct = 0; ct < 4; ct++) acc[rt][ct] = (f32x4){0.f, 0.f, 0.f, 0.f};
    {
        const unsigned short* wb = (const unsigned short*)(ws + OFF_WMB) + (size_t)b * 32768u;
#pragma unroll
        for (int kk = 0; kk < 4; kk++) {
            int ko = kk * 32 + lk * 8;
            bf16x8 a[4];
#pragma unroll
            for (int rt = 0; rt < 4; rt++)
                a[rt] = *(const bf16x8*)(xs + (rt * 16 + lrow) * LDP + ko);
            bf16x8 bf[4];
#pragma unroll
            for (int ct = 0; ct < 4; ct++)
                bf[ct] = *(const bf16x8*)(wb + (size_t)(colbase + ct * 16 + lrow) * DIN + ko);
#pragma unroll
            for (int rt = 0; rt < 4; rt++)
#pragma unroll
                for (int ct = 0; ct < 4; ct++)
                    acc[rt][ct] = __builtin_amdgcn_mfma_f32_16x16x32_bf16(a[rt], bf[ct], acc[rt][ct], 0, 0, 0);
        }
#pragma unroll
        for (int ct = 0; ct < 4; ct++) {
            float bv = ws[OFF_TB + b * DOUT + colbase + ct * 16 + lrow];
#pragma unroll
            for (int rt = 0; rt < 4; rt++)
#pragma unroll
                for (int r = 0; r < 4; r++) acc[rt][ct][r] += bv;
        }
    }

    // ---- per-n partial BN stats: reduce over this wave's 64 cols, then block, then atomics ----
    float s1[4][4], s2[4][4];
#pragma unroll
    for (int rt = 0; rt < 4; rt++)
#pragma unroll
        for (int r = 0; r < 4; r++) { s1[rt][r] = 0.f; s2[rt][r] = 0.f; }
#pragma unroll
    for (int rt = 0; rt < 4; rt++)
#pragma unroll
        for (int ct = 0; ct < 4; ct++)
#pragma unroll
            for (int r = 0; r < 4; r++) {
                float v = acc[rt][ct][r];
                s1[rt][r] += v; s2[rt][r] += v * v;
            }
#pragma unroll
    for (int off = 1; off < 16; off <<= 1) {
#pragma unroll
        for (int rt = 0; rt < 4; rt++)
#pragma unroll
            for (int r = 0; r < 4; r++) {
                s1[rt][r] += __shfl_xor(s1[rt][r], off, 64);
                s2[rt][r] += __shfl_xor(s2[rt][r], off, 64);
            }
    }
    if (lrow == 0) {
#pragma unroll
        for (int rt = 0; rt < 4; rt++)
#pragma unroll
            for (int r = 0; r < 4; r++) {
                int nidx = rt * 16 + lk * 4 + r;
                sp1[wid][nidx] = s1[rt][r];
                sp2[wid][nidx] = s2[rt][r];
            }
    }
    __syncthreads();
    float* stats = ws + OFF_STATS;
    if (t < 64) {
        float S1 = sp1[0][t] + sp1[1][t] + sp1[2][t] + sp1[3][t];
        float S2 = sp2[0][t] + sp2[1][t] + sp2[2][t] + sp2[3][t];
        atomicAdd(stats + (size_t)(n0 + t) * 2, S1);
        atomicAdd(stats + (size_t)(n0 + t) * 2 + 1, S2);
    }
    __syncthreads();   // all waves' atomics drained (vmcnt(0) at barrier)

    // ---- per-n-tile arrival barrier: wait for all 32 b-blocks of this nt ----
    unsigned* cnt = (unsigned*)(ws + OFF_CNT) + nt;
    if (t == 0) { __threadfence(); atomicAdd(cnt, 1u); }
    while (__hip_atomic_load(cnt, __ATOMIC_RELAXED, __HIP_MEMORY_SCOPE_AGENT) < (unsigned)BB)
        __builtin_amdgcn_s_sleep(8);
    __threadfence();   // acquire: stats reads below see all blocks' adds

    if (t < 64) {
        int n = n0 + t;
        float S1 = stats[(size_t)n * 2], S2 = stats[(size_t)n * 2 + 1];
        float mean = S1 * (1.f / 8192.f);
        float var  = S2 * (1.f / 8192.f) - mean * mean;
        float sc = gamma[n] * rsqrtf(fmaxf(var, 0.f) + 1e-5f);
        scs[t] = sc;
        shs[t] = beta[n] - mean * sc;
    }
    __syncthreads();

    // ---- epilogue straight from registers: out = (x1 + relu(bn(tt)))*g + hb ----
    float gv[4], hbv[4];
#pragma unroll
    for (int ct = 0; ct < 4; ct++) {
        int o = colbase + ct * 16 + lrow;
        gv[ct]  = ws[OFF_G  + b * DOUT + o];
        hbv[ct] = ws[OFF_HB + b * DOUT + o];
    }
#pragma unroll
    for (int rt = 0; rt < 4; rt++)
#pragma unroll
        for (int r = 0; r < 4; r++) {
            int nidx = rt * 16 + lk * 4 + r;
            float sc = scs[nidx], sh = shs[nidx];
            int n = n0 + nidx;
#pragma unroll
            for (int ct = 0; ct < 4; ct++) {
                int o = colbase + ct * 16 + lrow;
                float x1v = bf2f(x1p[(size_t)((b * NN + n) * DOUT) + o]);
                float rv = fmaxf(acc[rt][ct][r] * sc + sh, 0.f);
                out[(size_t)((b * NN + n) * DOUT) + o] = (x1v + rv) * gv[ct] + hbv[ct];
            }
        }
}

extern "C" void kernel_launch(void* const* d_in, const int* in_sizes, int n_in,
                              void* d_out, int out_size, void* d_ws, size_t ws_size,
                              hipStream_t stream) {
    const float* ctx   = (const float*)d_in[0];
    const float* x     = (const float*)d_in[1];
    const float* Wl    = (const float*)d_in[2];
    const float* bl    = (const float*)d_in[3];
    const float* Whb   = (const float*)d_in[4];
    const float* Wg    = (const float*)d_in[5];
    const float* bg    = (const float*)d_in[6];
    const float* Wk    = (const float*)d_in[7];
    const float* Wv    = (const float*)d_in[8];
    const float* Wtc   = (const float*)d_in[9];
    const float* btc   = (const float*)d_in[10];
    const float* gamma = (const float*)d_in[11];
    const float* beta  = (const float*)d_in[12];
    float* out = (float*)d_out;
    float* ws  = (float*)d_ws;

    kXW <<<45, 256, 0, stream>>>(Wl, Wtc, Wk, Wv, Wg, Whb, ws);
    kP  <<<BB, 1024, 0, stream>>>(ctx, bg, ws);
    k45 <<<dim3(2, BB), 512, 0, stream>>>(bl, btc, ws);
    kF  <<<dim3(32, BB), 256, 0, stream>>>(x, bl, gamma, beta, out, ws);
}

// Round 2
// 285.906 us; speedup vs baseline: 1.4999x; 1.4999x over previous
//
#include <hip/hip_runtime.h>
#include <hip/hip_bf16.h>

#define BB   32
#define NN   2048
#define DIN  128
#define DOUT 256
#define DCTX 259

// ---- workspace layout (float-slot offsets) ----
#define OFF_AB   0u          // A  bf16 [B][256][256] (dead before kF)
#define OFF_WMB  16777216u   // WM bf16 [B][256 e][128 i] = 524288
#define OFF_WLB  17301504u   // W_layer bf16 [256 o][128 i] = 16384
#define OFF_WLTB 17317888u   // W_layer^T bf16 [128 i][256 o] = 16384
#define OFF_WTCB 17334272u   // W_tc bf16 [256 e][256 o] = 32768
#define OFF_G    17367040u
#define OFF_HB   17375232u
#define OFF_TB   17383424u
#define OFF_WKT  17391616u   // [256 c][256 o] fp32
#define OFF_WVT  17457152u
#define OFF_WGT  17522688u   // [259 c][256 o]
#define OFF_WHT  17588992u
#define OFF_STATS 17655296u  // [2048 n][2] fp32 atomics (s1,s2)
#define OFF_CNT   17659392u  // [64 nt] arrival counters, padded 32 uints (128B) apart
// end 17661440 slots ≈ 70.6 MB

typedef short bf16x8 __attribute__((ext_vector_type(8)));
typedef float f32x4  __attribute__((ext_vector_type(4)));

static __device__ inline unsigned short f2bf(float f) {
    __hip_bfloat16 h = __float2bfloat16(f);
    return *(unsigned short*)&h;
}
static __device__ inline float bf2f(unsigned short u) {
    unsigned v = ((unsigned)u) << 16;
    float f;
    __builtin_memcpy(&f, &v, 4);
    return f;
}

// weight packing + stats/counter zeroing. grid 45.
__global__ void kXW(const float* __restrict__ Wl, const float* __restrict__ Wtc,
                    const float* __restrict__ Wk, const float* __restrict__ Wv,
                    const float* __restrict__ Wg, const float* __restrict__ Whb,
                    float* __restrict__ ws) {
    unsigned bb = blockIdx.x, t = threadIdx.x;
    if (bb < 8u) {
        unsigned base = bb * 8192u;
        unsigned short* dst = (unsigned short*)(ws + OFF_WTCB);
#pragma unroll
        for (int j = 0; j < 32; j++) {
            unsigned i = base + (unsigned)j * 256u + t;
            dst[i] = f2bf(Wtc[i]);
        }
    } else if (bb == 8u) {
        unsigned short* dst = (unsigned short*)(ws + OFF_WLTB);   // [i][o]
        for (unsigned idx = t; idx < 32768u; idx += 256u) {
            unsigned i = idx >> 8, o = idx & 255u;
            dst[idx] = f2bf(Wl[o * 128u + i]);
        }
    } else if (bb == 9u) {
        unsigned short* dst = (unsigned short*)(ws + OFF_WLB);    // [o][i]
        for (unsigned idx = t; idx < 32768u; idx += 256u) dst[idx] = f2bf(Wl[idx]);
    } else if (bb == 44u) {
        // zero BN stats accumulators (4096) + padded arrival counters (2048)
        for (unsigned i = t; i < 6144u; i += 256u) ws[OFF_STATS + i] = 0.f;
    } else {
        unsigned j = bb - 10u;
        const float* src; float* dst; unsigned C, c0;
        if (j < 8u)       { src = Wk;  dst = ws + OFF_WKT; C = 256; c0 = j * 32u; }
        else if (j < 16u) { src = Wv;  dst = ws + OFF_WVT; C = 256; c0 = (j - 8u) * 32u; }
        else if (j < 25u) { src = Wg;  dst = ws + OFF_WGT; C = 259; c0 = (j - 16u) * 32u; }
        else              { src = Whb; dst = ws + OFF_WHT; C = 259; c0 = (j - 25u) * 32u; }
        for (unsigned cc = c0; cc < c0 + 32u && cc < C; cc++)
            dst[cc * 256u + t] = src[t * C + cc];
    }
}

// Fused prep, 1024 threads: coalesced GEMVs + split softmax stats + A bf16. grid B.
__global__ __launch_bounds__(1024) void kP(const float* __restrict__ ctx,
                                           const float* __restrict__ bg,
                                           float* __restrict__ ws) {
    const int b = blockIdx.x, t = threadIdx.x;
    const int o = t & 255, q = t >> 8;
    __shared__ __align__(16) float cs[260];
    __shared__ __align__(16) float ks[256], vs[256], rms[256], ris[256];
    __shared__ float pm[1024], ps[1024];
    for (int i = t; i < DCTX; i += 1024) cs[i] = ctx[b * DCTX + i];
    __syncthreads();

    {
        const float* WT; int C;
        if (q == 0)      { WT = ws + OFF_WKT; C = 256; }
        else if (q == 1) { WT = ws + OFF_WVT; C = 256; }
        else if (q == 2) { WT = ws + OFF_WGT; C = DCTX; }
        else             { WT = ws + OFF_WHT; C = DCTX; }
        float s = 0.f;
#pragma unroll 8
        for (int c = 0; c < C; c++) s += WT[c * 256 + o] * cs[c];
        if (q == 0)      ks[o] = s;
        else if (q == 1) vs[o] = s;
        else if (q == 2) ws[OFF_G + b * DOUT + o] = 1.f / (1.f + __expf(-(s + bg[o])));
        else             ws[OFF_HB + b * DOUT + o] = s;
    }
    __syncthreads();

    const float ko = ks[o];
    const float4* vs4 = (const float4*)vs;
    float pmax = -1e30f;
#pragma unroll 4
    for (int j = q * 16; j < q * 16 + 16; j++) {
        float4 v = vs4[j];
        pmax = fmaxf(pmax, fmaxf(fmaxf(ko * v.x, ko * v.y), fmaxf(ko * v.z, ko * v.w)));
    }
    pm[q * 256 + o] = pmax;
    __syncthreads();
    float m = fmaxf(fmaxf(pm[o], pm[256 + o]), fmaxf(pm[512 + o], pm[768 + o]));
    float psum = 0.f;
#pragma unroll 4
    for (int j = q * 16; j < q * 16 + 16; j++) {
        float4 v = vs4[j];
        psum += __expf(ko * v.x - m) + __expf(ko * v.y - m)
              + __expf(ko * v.z - m) + __expf(ko * v.w - m);
    }
    ps[q * 256 + o] = psum;
    __syncthreads();
    float ri = 1.f / (ps[o] + ps[256 + o] + ps[512 + o] + ps[768 + o]);
    if (q == 0) { rms[o] = m; ris[o] = ri; }
    __syncthreads();

    const float ve = vs[o];
    float cp = 0.f;
#pragma unroll 4
    for (int o2 = q * 64; o2 < q * 64 + 64; o2++)
        cp += __expf(ks[o2] * ve - rms[o2]) * ris[o2];
    pm[q * 256 + o] = cp;
    __syncthreads();
    float ci = 1.f / (1e-9f + pm[o] + pm[256 + o] + pm[512 + o] + pm[768 + o]);
    unsigned short* Ab = (unsigned short*)(ws + OFF_AB) + (size_t)b * 65536u;
#pragma unroll 4
    for (int o2 = q * 64; o2 < q * 64 + 64; o2++) {
        float a = __expf(ks[o2] * ve - rms[o2]) * ris[o2] * ci;
        Ab[o2 * 256 + o] = f2bf(a);
    }
}

// Fused k4m+k5m: Mt (= Wtc - A-contraction) stays in LDS (XOR-swizzled, 16B granular),
// then WM = Mt @ Wl^T and tb GEMV. grid (2 e-halves, B), 512 threads (8 waves).
__global__ __launch_bounds__(512) void k45(const float* __restrict__ bl,
                                           const float* __restrict__ btc,
                                           float* __restrict__ ws) {
    const int t = threadIdx.x, wid = t >> 6, l = t & 63;
    const int b = blockIdx.y, et = blockIdx.x;
    const int lrow = l & 15, lk = l >> 4;
    __shared__ unsigned short Mt[128 * 256];   // 64 KB, swizzled: col ^ ((row&7)<<3)
    const unsigned short* Wtcb = (const unsigned short*)(ws + OFF_WTCB);

    // ---- phase A: Mt rows [et*128, et*128+128) ----
    {
        const unsigned short* Ab = (const unsigned short*)(ws + OFF_AB) + (size_t)b * 65536u;
        const int sub = wid >> 2, w2 = wid & 3;
        const int rbase = et * 128 + sub * 64 + (w2 & 1) * 32;
        const int colbase = (w2 >> 1) * 128;
        f32x4 acc[2][8];
#pragma unroll
        for (int i = 0; i < 2; i++)
#pragma unroll
            for (int c = 0; c < 8; c++) acc[i][c] = (f32x4){0.f, 0.f, 0.f, 0.f};
        const unsigned short* ar0 = Wtcb + (rbase + lrow) * 256;
#pragma unroll
        for (int kk = 0; kk < 8; kk++) {
            int ko = kk * 32 + lk * 8;
            bf16x8 a0 = *(const bf16x8*)(ar0 + ko);
            bf16x8 a1 = *(const bf16x8*)(ar0 + 16 * 256 + ko);
            bf16x8 bfr[8];
#pragma unroll
            for (int c = 0; c < 8; c++)
                bfr[c] = *(const bf16x8*)(Ab + (colbase + c * 16 + lrow) * 256 + ko);
#pragma unroll
            for (int c = 0; c < 8; c++) {
                acc[0][c] = __builtin_amdgcn_mfma_f32_16x16x32_bf16(a0, bfr[c], acc[0][c], 0, 0, 0);
                acc[1][c] = __builtin_amdgcn_mfma_f32_16x16x32_bf16(a1, bfr[c], acc[1][c], 0, 0, 0);
            }
        }
#pragma unroll
        for (int t2 = 0; t2 < 2; t2++)
#pragma unroll
            for (int c = 0; c < 8; c++)
#pragma unroll
                for (int r = 0; r < 4; r++) {
                    int grow = rbase + t2 * 16 + lk * 4 + r;
                    int col = colbase + c * 16 + lrow;
                    float idv = bf2f(Wtcb[grow * 256 + col]);
                    int rl = grow - et * 128;
                    Mt[rl * 256 + (col ^ ((rl & 7) << 3))] = f2bf(idv - acc[t2][c][r]);
                }
    }
    __syncthreads();
    // ---- phase B: WM rows = Mt @ Wl^T ----
    {
        const unsigned short* Wltb = (const unsigned short*)(ws + OFF_WLTB);
        const int rl0 = wid * 16;
        f32x4 acc[8];
#pragma unroll
        for (int c = 0; c < 8; c++) acc[c] = (f32x4){0.f, 0.f, 0.f, 0.f};
        const int arow = rl0 + lrow;
        const int asw = (arow & 7) << 3;
#pragma unroll
        for (int kk = 0; kk < 8; kk++) {
            int ko = kk * 32 + lk * 8;
            bf16x8 a0 = *(const bf16x8*)(Mt + arow * 256 + (ko ^ asw));
            bf16x8 bfr[8];
#pragma unroll
            for (int c = 0; c < 8; c++)
                bfr[c] = *(const bf16x8*)(Wltb + (c * 16 + lrow) * 256 + ko);
#pragma unroll
            for (int c = 0; c < 8; c++)
                acc[c] = __builtin_amdgcn_mfma_f32_16x16x32_bf16(a0, bfr[c], acc[c], 0, 0, 0);
        }
        unsigned short* WMBp = (unsigned short*)(ws + OFF_WMB) + (size_t)b * 32768u;
#pragma unroll
        for (int c = 0; c < 8; c++)
#pragma unroll
            for (int r = 0; r < 4; r++) {
                int row = et * 128 + rl0 + lk * 4 + r;
                int col = c * 16 + lrow;
                WMBp[row * 128 + col] = f2bf(acc[c][r]);
            }
    }
    // ---- tb bias GEMV from LDS Mt ----
    if (t < 128) {
        const int rl = t;
        const int sw = (rl & 7) << 3;
        float s = 0.f;
#pragma unroll 4
        for (int j = 0; j < 32; j++) {
            bf16x8 ch = *(const bf16x8*)(Mt + rl * 256 + ((j * 8) ^ sw));
#pragma unroll
            for (int u = 0; u < 8; u++) s += bl[j * 8 + u] * bf2f((unsigned short)ch[u]);
        }
        ws[OFF_TB + b * DOUT + et * 128 + rl] = s + btc[et * 128 + rl];
    }
}

// Fused dual-GEMM + BN stats + epilogue. Both tt AND x1 stay in registers (x1 never
// materialized). 32 n-rows per block, grid (b fastest=32, nt=64): any 32 consecutive
// dispatched blocks form a complete sibling group -> forward progress at any occupancy.
// Barrier: stats atomicAdd -> release counter add (early) -> x1 pass -> single-thread
// acquire spin on 128B-padded counter (late) -> epilogue from registers.
#define LDP 136
__global__ __launch_bounds__(256, 4) void kF(const float* __restrict__ x,
                                             const float* __restrict__ bl,
                                             const float* __restrict__ gamma,
                                             const float* __restrict__ beta,
                                             float* __restrict__ out,
                                             float* __restrict__ ws) {
    const int t = threadIdx.x;
    const int wid = t >> 6, l = t & 63;
    const int b = blockIdx.x;          // fastest dim: sibling groups dispatch together
    const int nt = blockIdx.y;
    const int n0 = nt * 32;
    const int lrow = l & 15, lk = l >> 4;
    __shared__ unsigned short xs[32 * LDP];
    __shared__ float sp1[4][32], sp2[4][32];
    __shared__ float scs[32], shs[32];

    // stage x tile (32 rows x 128 k) fp32 -> bf16 LDS, coalesced 16B loads
    const float4* xg = (const float4*)(x + (size_t)(b * NN + n0) * DIN);
#pragma unroll
    for (int it = 0; it < 4; it++) {
        int idx = it * 256 + t;
        int row = idx >> 5, kq = idx & 31;
        float4 v = xg[idx];
        ushort4 u;
        u.x = f2bf(v.x); u.y = f2bf(v.y); u.z = f2bf(v.z); u.w = f2bf(v.w);
        *(ushort4*)(xs + row * LDP + kq * 4) = u;
    }
    __syncthreads();

    const int colbase = wid * 64;

    // ---- pass 1: tt = x @ WM^T + tb -> registers ----
    f32x4 acc[2][4];
#pragma unroll
    for (int rt = 0; rt < 2; rt++)
#pragma unroll
        for (int ct = 0; ct < 4; ct++) acc[rt][ct] = (f32x4){0.f, 0.f, 0.f, 0.f};
    {
        const unsigned short* wb = (const unsigned short*)(ws + OFF_WMB) + (size_t)b * 32768u;
#pragma unroll
        for (int kk = 0; kk < 4; kk++) {
            int ko = kk * 32 + lk * 8;
            bf16x8 a[2];
#pragma unroll
            for (int rt = 0; rt < 2; rt++)
                a[rt] = *(const bf16x8*)(xs + (rt * 16 + lrow) * LDP + ko);
            bf16x8 bf[4];
#pragma unroll
            for (int ct = 0; ct < 4; ct++)
                bf[ct] = *(const bf16x8*)(wb + (size_t)(colbase + ct * 16 + lrow) * DIN + ko);
#pragma unroll
            for (int rt = 0; rt < 2; rt++)
#pragma unroll
                for (int ct = 0; ct < 4; ct++)
                    acc[rt][ct] = __builtin_amdgcn_mfma_f32_16x16x32_bf16(a[rt], bf[ct], acc[rt][ct], 0, 0, 0);
        }
#pragma unroll
        for (int ct = 0; ct < 4; ct++) {
            float bv = ws[OFF_TB + b * DOUT + colbase + ct * 16 + lrow];
#pragma unroll
            for (int rt = 0; rt < 2; rt++)
#pragma unroll
                for (int r = 0; r < 4; r++) acc[rt][ct][r] += bv;
        }
    }

    // ---- per-n partial BN stats: wave reduce over 64 cols -> LDS -> atomics ----
    {
        float s1[2][4], s2[2][4];
#pragma unroll
        for (int rt = 0; rt < 2; rt++)
#pragma unroll
            for (int r = 0; r < 4; r++) { s1[rt][r] = 0.f; s2[rt][r] = 0.f; }
#pragma unroll
        for (int rt = 0; rt < 2; rt++)
#pragma unroll
            for (int ct = 0; ct < 4; ct++)
#pragma unroll
                for (int r = 0; r < 4; r++) {
                    float v = acc[rt][ct][r];
                    s1[rt][r] += v; s2[rt][r] += v * v;
                }
#pragma unroll
        for (int off = 1; off < 16; off <<= 1) {
#pragma unroll
            for (int rt = 0; rt < 2; rt++)
#pragma unroll
                for (int r = 0; r < 4; r++) {
                    s1[rt][r] += __shfl_xor(s1[rt][r], off, 64);
                    s2[rt][r] += __shfl_xor(s2[rt][r], off, 64);
                }
        }
        if (lrow == 0) {
#pragma unroll
            for (int rt = 0; rt < 2; rt++)
#pragma unroll
                for (int r = 0; r < 4; r++) {
                    int nidx = rt * 16 + lk * 4 + r;
                    sp1[wid][nidx] = s1[rt][r];
                    sp2[wid][nidx] = s2[rt][r];
                }
        }
    }
    __syncthreads();
    float* stats = ws + OFF_STATS;
    if (t < 32) {
        float S1 = sp1[0][t] + sp1[1][t] + sp1[2][t] + sp1[3][t];
        float S2 = sp2[0][t] + sp2[1][t] + sp2[2][t] + sp2[3][t];
        atomicAdd(stats + (size_t)(n0 + t) * 2, S1);
        atomicAdd(stats + (size_t)(n0 + t) * 2 + 1, S2);
    }
    __syncthreads();   // drains the atomics (vmcnt(0) before s_barrier)

    unsigned* cnt = (unsigned*)(ws + OFF_CNT) + (size_t)nt * 32;   // 128B-padded
    if (t == 0)
        __hip_atomic_fetch_add(cnt, 1u, __ATOMIC_RELEASE, __HIP_MEMORY_SCOPE_AGENT);

    // ---- pass 0 (between arrive and wait): x1 = x @ Wl^T + bl -> registers ----
    f32x4 acc0[2][4];
#pragma unroll
    for (int rt = 0; rt < 2; rt++)
#pragma unroll
        for (int ct = 0; ct < 4; ct++) acc0[rt][ct] = (f32x4){0.f, 0.f, 0.f, 0.f};
    {
        const unsigned short* wb = (const unsigned short*)(ws + OFF_WLB);
#pragma unroll
        for (int kk = 0; kk < 4; kk++) {
            int ko = kk * 32 + lk * 8;
            bf16x8 a[2];
#pragma unroll
            for (int rt = 0; rt < 2; rt++)
                a[rt] = *(const bf16x8*)(xs + (rt * 16 + lrow) * LDP + ko);
            bf16x8 bf[4];
#pragma unroll
            for (int ct = 0; ct < 4; ct++)
                bf[ct] = *(const bf16x8*)(wb + (size_t)(colbase + ct * 16 + lrow) * DIN + ko);
#pragma unroll
            for (int rt = 0; rt < 2; rt++)
#pragma unroll
                for (int ct = 0; ct < 4; ct++)
                    acc0[rt][ct] = __builtin_amdgcn_mfma_f32_16x16x32_bf16(a[rt], bf[ct], acc0[rt][ct], 0, 0, 0);
        }
#pragma unroll
        for (int ct = 0; ct < 4; ct++) {
            float bv = bl[colbase + ct * 16 + lrow];
#pragma unroll
            for (int rt = 0; rt < 2; rt++)
#pragma unroll
                for (int r = 0; r < 4; r++) acc0[rt][ct][r] += bv;
        }
    }

    // ---- single-thread acquire spin on this nt's padded counter ----
    if (t == 0) {
        while (__hip_atomic_load(cnt, __ATOMIC_ACQUIRE, __HIP_MEMORY_SCOPE_AGENT) < (unsigned)BB)
            __builtin_amdgcn_s_sleep(32);
    }
    __syncthreads();

    if (t < 32) {
        int n = n0 + t;
        float S1 = __hip_atomic_load(stats + (size_t)n * 2,     __ATOMIC_RELAXED, __HIP_MEMORY_SCOPE_AGENT);
        float S2 = __hip_atomic_load(stats + (size_t)n * 2 + 1, __ATOMIC_RELAXED, __HIP_MEMORY_SCOPE_AGENT);
        float mean = S1 * (1.f / 8192.f);
        float var  = S2 * (1.f / 8192.f) - mean * mean;
        float sc = gamma[n] * rsqrtf(fmaxf(var, 0.f) + 1e-5f);
        scs[t] = sc;
        shs[t] = beta[n] - mean * sc;
    }
    __syncthreads();

    // ---- epilogue straight from registers: out = (x1 + relu(bn(tt)))*g + hb ----
    float gv[4], hbv[4];
#pragma unroll
    for (int ct = 0; ct < 4; ct++) {
        int o = colbase + ct * 16 + lrow;
        gv[ct]  = ws[OFF_G  + b * DOUT + o];
        hbv[ct] = ws[OFF_HB + b * DOUT + o];
    }
#pragma unroll
    for (int rt = 0; rt < 2; rt++)
#pragma unroll
        for (int r = 0; r < 4; r++) {
            int nidx = rt * 16 + lk * 4 + r;
            float sc = scs[nidx], sh = shs[nidx];
            int n = n0 + nidx;
#pragma unroll
            for (int ct = 0; ct < 4; ct++) {
                int o = colbase + ct * 16 + lrow;
                float rv = fmaxf(acc[rt][ct][r] * sc + sh, 0.f);
                out[(size_t)((b * NN + n) * DOUT) + o] = (acc0[rt][ct][r] + rv) * gv[ct] + hbv[ct];
            }
        }
}

extern "C" void kernel_launch(void* const* d_in, const int* in_sizes, int n_in,
                              void* d_out, int out_size, void* d_ws, size_t ws_size,
                              hipStream_t stream) {
    const float* ctx   = (const float*)d_in[0];
    const float* x     = (const float*)d_in[1];
    const float* Wl    = (const float*)d_in[2];
    const float* bl    = (const float*)d_in[3];
    const float* Whb   = (const float*)d_in[4];
    const float* Wg    = (const float*)d_in[5];
    const float* bg    = (const float*)d_in[6];
    const float* Wk    = (const float*)d_in[7];
    const float* Wv    = (const float*)d_in[8];
    const float* Wtc   = (const float*)d_in[9];
    const float* btc   = (const float*)d_in[10];
    const float* gamma = (const float*)d_in[11];
    const float* beta  = (const float*)d_in[12];
    float* out = (float*)d_out;
    float* ws  = (float*)d_ws;

    kXW <<<45, 256, 0, stream>>>(Wl, Wtc, Wk, Wv, Wg, Whb, ws);
    kP  <<<BB, 1024, 0, stream>>>(ctx, bg, ws);
    k45 <<<dim3(2, BB), 512, 0, stream>>>(bl, btc, ws);
    kF  <<<dim3(BB, 64), 256, 0, stream>>>(x, bl, gamma, beta, out, ws);
}

// Round 3
// 247.001 us; speedup vs baseline: 1.7362x; 1.1575x over previous
//
#include <hip/hip_runtime.h>
#include <hip/hip_bf16.h>

#define BB   32
#define NN   2048
#define DIN  128
#define DOUT 256
#define DCTX 259

// ---- workspace layout (float-slot offsets) ----
#define OFF_AB   0u          // A  bf16 [B][256][256] (dead before kF)
#define OFF_WMB  16777216u   // WM bf16 [B][256 e][128 i] = 524288
#define OFF_WLB  17301504u   // W_layer bf16 [256 o][128 i] = 16384
#define OFF_WLTB 17317888u   // W_layer^T bf16 [128 i][256 o] = 16384
#define OFF_WTCB 17334272u   // W_tc bf16 [256 e][256 o] = 32768
#define OFF_G    17367040u
#define OFF_HB   17375232u
#define OFF_TB   17383424u
#define OFF_WKT  17391616u   // [256 c][256 o] fp32
#define OFF_WVT  17457152u
#define OFF_WGT  17522688u   // [259 c][256 o]
#define OFF_WHT  17588992u
#define OFF_P1   17655296u   // BN partial s1 [32 b][2048 n] fp32 (overwritten each iter)
#define OFF_P2   17720832u   // BN partial s2 [32 b][2048 n] fp32
#define OFF_SC   17786368u   // sc[n] fp32
#define OFF_SH   17788416u   // sh[n] fp32
// end 17790464 slots ≈ 71.2 MB

typedef short bf16x8 __attribute__((ext_vector_type(8)));
typedef float f32x4  __attribute__((ext_vector_type(4)));

static __device__ inline unsigned short f2bf(float f) {
    __hip_bfloat16 h = __float2bfloat16(f);
    return *(unsigned short*)&h;
}
static __device__ inline float bf2f(unsigned short u) {
    unsigned v = ((unsigned)u) << 16;
    float f;
    __builtin_memcpy(&f, &v, 4);
    return f;
}

// weight packing. grid 44.
__global__ void kXW(const float* __restrict__ Wl, const float* __restrict__ Wtc,
                    const float* __restrict__ Wk, const float* __restrict__ Wv,
                    const float* __restrict__ Wg, const float* __restrict__ Whb,
                    float* __restrict__ ws) {
    unsigned bb = blockIdx.x, t = threadIdx.x;
    if (bb < 8u) {
        unsigned base = bb * 8192u;
        unsigned short* dst = (unsigned short*)(ws + OFF_WTCB);
#pragma unroll
        for (int j = 0; j < 32; j++) {
            unsigned i = base + (unsigned)j * 256u + t;
            dst[i] = f2bf(Wtc[i]);
        }
    } else if (bb == 8u) {
        unsigned short* dst = (unsigned short*)(ws + OFF_WLTB);   // [i][o]
        for (unsigned idx = t; idx < 32768u; idx += 256u) {
            unsigned i = idx >> 8, o = idx & 255u;
            dst[idx] = f2bf(Wl[o * 128u + i]);
        }
    } else if (bb == 9u) {
        unsigned short* dst = (unsigned short*)(ws + OFF_WLB);    // [o][i]
        for (unsigned idx = t; idx < 32768u; idx += 256u) dst[idx] = f2bf(Wl[idx]);
    } else {
        unsigned j = bb - 10u;
        const float* src; float* dst; unsigned C, c0;
        if (j < 8u)       { src = Wk;  dst = ws + OFF_WKT; C = 256; c0 = j * 32u; }
        else if (j < 16u) { src = Wv;  dst = ws + OFF_WVT; C = 256; c0 = (j - 8u) * 32u; }
        else if (j < 25u) { src = Wg;  dst = ws + OFF_WGT; C = 259; c0 = (j - 16u) * 32u; }
        else              { src = Whb; dst = ws + OFF_WHT; C = 259; c0 = (j - 25u) * 32u; }
        for (unsigned cc = c0; cc < c0 + 32u && cc < C; cc++)
            dst[cc * 256u + t] = src[t * C + cc];
    }
}

// Fused prep, 1024 threads: coalesced GEMVs + split softmax stats + A bf16. grid B.
__global__ __launch_bounds__(1024) void kP(const float* __restrict__ ctx,
                                           const float* __restrict__ bg,
                                           float* __restrict__ ws) {
    const int b = blockIdx.x, t = threadIdx.x;
    const int o = t & 255, q = t >> 8;
    __shared__ __align__(16) float cs[260];
    __shared__ __align__(16) float ks[256], vs[256], rms[256], ris[256];
    __shared__ float pm[1024], ps[1024];
    for (int i = t; i < DCTX; i += 1024) cs[i] = ctx[b * DCTX + i];
    __syncthreads();

    {
        const float* WT; int C;
        if (q == 0)      { WT = ws + OFF_WKT; C = 256; }
        else if (q == 1) { WT = ws + OFF_WVT; C = 256; }
        else if (q == 2) { WT = ws + OFF_WGT; C = DCTX; }
        else             { WT = ws + OFF_WHT; C = DCTX; }
        float s = 0.f;
#pragma unroll 8
        for (int c = 0; c < C; c++) s += WT[c * 256 + o] * cs[c];
        if (q == 0)      ks[o] = s;
        else if (q == 1) vs[o] = s;
        else if (q == 2) ws[OFF_G + b * DOUT + o] = 1.f / (1.f + __expf(-(s + bg[o])));
        else             ws[OFF_HB + b * DOUT + o] = s;
    }
    __syncthreads();

    const float ko = ks[o];
    const float4* vs4 = (const float4*)vs;
    float pmax = -1e30f;
#pragma unroll 4
    for (int j = q * 16; j < q * 16 + 16; j++) {
        float4 v = vs4[j];
        pmax = fmaxf(pmax, fmaxf(fmaxf(ko * v.x, ko * v.y), fmaxf(ko * v.z, ko * v.w)));
    }
    pm[q * 256 + o] = pmax;
    __syncthreads();
    float m = fmaxf(fmaxf(pm[o], pm[256 + o]), fmaxf(pm[512 + o], pm[768 + o]));
    float psum = 0.f;
#pragma unroll 4
    for (int j = q * 16; j < q * 16 + 16; j++) {
        float4 v = vs4[j];
        psum += __expf(ko * v.x - m) + __expf(ko * v.y - m)
              + __expf(ko * v.z - m) + __expf(ko * v.w - m);
    }
    ps[q * 256 + o] = psum;
    __syncthreads();
    float ri = 1.f / (ps[o] + ps[256 + o] + ps[512 + o] + ps[768 + o]);
    if (q == 0) { rms[o] = m; ris[o] = ri; }
    __syncthreads();

    const float ve = vs[o];
    float cp = 0.f;
#pragma unroll 4
    for (int o2 = q * 64; o2 < q * 64 + 64; o2++)
        cp += __expf(ks[o2] * ve - rms[o2]) * ris[o2];
    pm[q * 256 + o] = cp;
    __syncthreads();
    float ci = 1.f / (1e-9f + pm[o] + pm[256 + o] + pm[512 + o] + pm[768 + o]);
    unsigned short* Ab = (unsigned short*)(ws + OFF_AB) + (size_t)b * 65536u;
#pragma unroll 4
    for (int o2 = q * 64; o2 < q * 64 + 64; o2++) {
        float a = __expf(ks[o2] * ve - rms[o2]) * ris[o2] * ci;
        Ab[o2 * 256 + o] = f2bf(a);
    }
}

// Fused k4m+k5m: Mt (= Wtc - A-contraction) stays in LDS (XOR-swizzled, 16B granular),
// then WM = Mt @ Wl^T and tb GEMV. grid (2 e-halves, B), 512 threads (8 waves).
__global__ __launch_bounds__(512) void k45(const float* __restrict__ bl,
                                           const float* __restrict__ btc,
                                           float* __restrict__ ws) {
    const int t = threadIdx.x, wid = t >> 6, l = t & 63;
    const int b = blockIdx.y, et = blockIdx.x;
    const int lrow = l & 15, lk = l >> 4;
    __shared__ unsigned short Mt[128 * 256];   // 64 KB, swizzled: col ^ ((row&7)<<3)
    const unsigned short* Wtcb = (const unsigned short*)(ws + OFF_WTCB);

    // ---- phase A: Mt rows [et*128, et*128+128) ----
    {
        const unsigned short* Ab = (const unsigned short*)(ws + OFF_AB) + (size_t)b * 65536u;
        const int sub = wid >> 2, w2 = wid & 3;
        const int rbase = et * 128 + sub * 64 + (w2 & 1) * 32;
        const int colbase = (w2 >> 1) * 128;
        f32x4 acc[2][8];
#pragma unroll
        for (int i = 0; i < 2; i++)
#pragma unroll
            for (int c = 0; c < 8; c++) acc[i][c] = (f32x4){0.f, 0.f, 0.f, 0.f};
        const unsigned short* ar0 = Wtcb + (rbase + lrow) * 256;
#pragma unroll
        for (int kk = 0; kk < 8; kk++) {
            int ko = kk * 32 + lk * 8;
            bf16x8 a0 = *(const bf16x8*)(ar0 + ko);
            bf16x8 a1 = *(const bf16x8*)(ar0 + 16 * 256 + ko);
            bf16x8 bfr[8];
#pragma unroll
            for (int c = 0; c < 8; c++)
                bfr[c] = *(const bf16x8*)(Ab + (colbase + c * 16 + lrow) * 256 + ko);
#pragma unroll
            for (int c = 0; c < 8; c++) {
                acc[0][c] = __builtin_amdgcn_mfma_f32_16x16x32_bf16(a0, bfr[c], acc[0][c], 0, 0, 0);
                acc[1][c] = __builtin_amdgcn_mfma_f32_16x16x32_bf16(a1, bfr[c], acc[1][c], 0, 0, 0);
            }
        }
#pragma unroll
        for (int t2 = 0; t2 < 2; t2++)
#pragma unroll
            for (int c = 0; c < 8; c++)
#pragma unroll
                for (int r = 0; r < 4; r++) {
                    int grow = rbase + t2 * 16 + lk * 4 + r;
                    int col = colbase + c * 16 + lrow;
                    float idv = bf2f(Wtcb[grow * 256 + col]);
                    int rl = grow - et * 128;
                    Mt[rl * 256 + (col ^ ((rl & 7) << 3))] = f2bf(idv - acc[t2][c][r]);
                }
    }
    __syncthreads();
    // ---- phase B: WM rows = Mt @ Wl^T ----
    {
        const unsigned short* Wltb = (const unsigned short*)(ws + OFF_WLTB);
        const int rl0 = wid * 16;
        f32x4 acc[8];
#pragma unroll
        for (int c = 0; c < 8; c++) acc[c] = (f32x4){0.f, 0.f, 0.f, 0.f};
        const int arow = rl0 + lrow;
        const int asw = (arow & 7) << 3;
#pragma unroll
        for (int kk = 0; kk < 8; kk++) {
            int ko = kk * 32 + lk * 8;
            bf16x8 a0 = *(const bf16x8*)(Mt + arow * 256 + (ko ^ asw));
            bf16x8 bfr[8];
#pragma unroll
            for (int c = 0; c < 8; c++)
                bfr[c] = *(const bf16x8*)(Wltb + (c * 16 + lrow) * 256 + ko);
#pragma unroll
            for (int c = 0; c < 8; c++)
                acc[c] = __builtin_amdgcn_mfma_f32_16x16x32_bf16(a0, bfr[c], acc[c], 0, 0, 0);
        }
        unsigned short* WMBp = (unsigned short*)(ws + OFF_WMB) + (size_t)b * 32768u;
#pragma unroll
        for (int c = 0; c < 8; c++)
#pragma unroll
            for (int r = 0; r < 4; r++) {
                int row = et * 128 + rl0 + lk * 4 + r;
                int col = c * 16 + lrow;
                WMBp[row * 128 + col] = f2bf(acc[c][r]);
            }
    }
    // ---- tb bias GEMV from LDS Mt ----
    if (t < 128) {
        const int rl = t;
        const int sw = (rl & 7) << 3;
        float s = 0.f;
#pragma unroll 4
        for (int j = 0; j < 32; j++) {
            bf16x8 ch = *(const bf16x8*)(Mt + rl * 256 + ((j * 8) ^ sw));
#pragma unroll
            for (int u = 0; u < 8; u++) s += bl[j * 8 + u] * bf2f((unsigned short)ch[u]);
        }
        ws[OFF_TB + b * DOUT + et * 128 + rl] = s + btc[et * 128 + rl];
    }
}

#define LDP 136

// BN-stats GEMM: recompute tt = x @ WM^T + tb (bit-identical to kF's), reduce rows
// to (s1,s2), write atomic-free partials part[b][n]. grid (32 b, 32 nt), 256 thr.
__global__ __launch_bounds__(256) void kS(const float* __restrict__ x,
                                          float* __restrict__ ws) {
    const int t = threadIdx.x;
    const int wid = t >> 6, l = t & 63;
    const int b = blockIdx.x, nt = blockIdx.y;
    const int n0 = nt * 64;
    const int lrow = l & 15, lk = l >> 4;
    __shared__ unsigned short xs[64 * LDP];
    __shared__ float sp1[4][64], sp2[4][64];

    const float4* xg = (const float4*)(x + (size_t)(b * NN + n0) * DIN);
#pragma unroll
    for (int it = 0; it < 8; it++) {
        int idx = it * 256 + t;
        int row = idx >> 5, kq = idx & 31;
        float4 v = xg[idx];
        ushort4 u;
        u.x = f2bf(v.x); u.y = f2bf(v.y); u.z = f2bf(v.z); u.w = f2bf(v.w);
        *(ushort4*)(xs + row * LDP + kq * 4) = u;
    }
    __syncthreads();

    const int colbase = wid * 64;
    f32x4 acc[4][4];
#pragma unroll
    for (int rt = 0; rt < 4; rt++)
#pragma unroll
        for (int ct = 0; ct < 4; ct++) acc[rt][ct] = (f32x4){0.f, 0.f, 0.f, 0.f};
    {
        const unsigned short* wb = (const unsigned short*)(ws + OFF_WMB) + (size_t)b * 32768u;
#pragma unroll
        for (int kk = 0; kk < 4; kk++) {
            int ko = kk * 32 + lk * 8;
            bf16x8 a[4];
#pragma unroll
            for (int rt = 0; rt < 4; rt++)
                a[rt] = *(const bf16x8*)(xs + (rt * 16 + lrow) * LDP + ko);
            bf16x8 bf[4];
#pragma unroll
            for (int ct = 0; ct < 4; ct++)
                bf[ct] = *(const bf16x8*)(wb + (size_t)(colbase + ct * 16 + lrow) * DIN + ko);
#pragma unroll
            for (int rt = 0; rt < 4; rt++)
#pragma unroll
                for (int ct = 0; ct < 4; ct++)
                    acc[rt][ct] = __builtin_amdgcn_mfma_f32_16x16x32_bf16(a[rt], bf[ct], acc[rt][ct], 0, 0, 0);
        }
#pragma unroll
        for (int ct = 0; ct < 4; ct++) {
            float bv = ws[OFF_TB + b * DOUT + colbase + ct * 16 + lrow];
#pragma unroll
            for (int rt = 0; rt < 4; rt++)
#pragma unroll
                for (int r = 0; r < 4; r++) acc[rt][ct][r] += bv;
        }
    }

    float s1[4][4], s2[4][4];
#pragma unroll
    for (int rt = 0; rt < 4; rt++)
#pragma unroll
        for (int r = 0; r < 4; r++) { s1[rt][r] = 0.f; s2[rt][r] = 0.f; }
#pragma unroll
    for (int rt = 0; rt < 4; rt++)
#pragma unroll
        for (int ct = 0; ct < 4; ct++)
#pragma unroll
            for (int r = 0; r < 4; r++) {
                float v = acc[rt][ct][r];
                s1[rt][r] += v; s2[rt][r] += v * v;
            }
#pragma unroll
    for (int off = 1; off < 16; off <<= 1) {
#pragma unroll
        for (int rt = 0; rt < 4; rt++)
#pragma unroll
            for (int r = 0; r < 4; r++) {
                s1[rt][r] += __shfl_xor(s1[rt][r], off, 64);
                s2[rt][r] += __shfl_xor(s2[rt][r], off, 64);
            }
    }
    if (lrow == 0) {
#pragma unroll
        for (int rt = 0; rt < 4; rt++)
#pragma unroll
            for (int r = 0; r < 4; r++) {
                int nidx = rt * 16 + lk * 4 + r;
                sp1[wid][nidx] = s1[rt][r];
                sp2[wid][nidx] = s2[rt][r];
            }
    }
    __syncthreads();
    if (t < 64) {
        float S1 = sp1[0][t] + sp1[1][t] + sp1[2][t] + sp1[3][t];
        float S2 = sp2[0][t] + sp2[1][t] + sp2[2][t] + sp2[3][t];
        ws[OFF_P1 + (size_t)b * NN + n0 + t] = S1;   // coalesced, no atomics
        ws[OFF_P2 + (size_t)b * NN + n0 + t] = S2;
    }
}

// Finalize BN: sum 32 partials per n, emit sc/sh. grid 8 x 256.
__global__ __launch_bounds__(256) void kBN(const float* __restrict__ gamma,
                                           const float* __restrict__ beta,
                                           float* __restrict__ ws) {
    const int n = blockIdx.x * 256 + threadIdx.x;
    float S1 = 0.f, S2 = 0.f;
#pragma unroll 8
    for (int b = 0; b < BB; b++) {
        S1 += ws[OFF_P1 + (size_t)b * NN + n];
        S2 += ws[OFF_P2 + (size_t)b * NN + n];
    }
    float mean = S1 * (1.f / 8192.f);
    float var  = S2 * (1.f / 8192.f) - mean * mean;
    float sc = gamma[n] * rsqrtf(fmaxf(var, 0.f) + 1e-5f);
    ws[OFF_SC + n] = sc;
    ws[OFF_SH + n] = beta[n] - mean * sc;
}

// Fused dual-GEMM + epilogue, fully stream-ordered (no atomics, no spin).
// tt and x1 both stay in registers; sc/sh precomputed by kBN. grid (32 b, 64 nt).
__global__ __launch_bounds__(256, 4) void kF(const float* __restrict__ x,
                                             const float* __restrict__ bl,
                                             float* __restrict__ out,
                                             float* __restrict__ ws) {
    const int t = threadIdx.x;
    const int wid = t >> 6, l = t & 63;
    const int b = blockIdx.x;
    const int nt = blockIdx.y;
    const int n0 = nt * 32;
    const int lrow = l & 15, lk = l >> 4;
    __shared__ unsigned short xs[32 * LDP];
    __shared__ float scs[32], shs[32];

    if (t < 32) {
        scs[t] = ws[OFF_SC + n0 + t];
        shs[t] = ws[OFF_SH + n0 + t];
    }
    const float4* xg = (const float4*)(x + (size_t)(b * NN + n0) * DIN);
#pragma unroll
    for (int it = 0; it < 4; it++) {
        int idx = it * 256 + t;
        int row = idx >> 5, kq = idx & 31;
        float4 v = xg[idx];
        ushort4 u;
        u.x = f2bf(v.x); u.y = f2bf(v.y); u.z = f2bf(v.z); u.w = f2bf(v.w);
        *(ushort4*)(xs + row * LDP + kq * 4) = u;
    }
    __syncthreads();

    const int colbase = wid * 64;

    // ---- pass 1: tt = x @ WM^T + tb -> registers ----
    f32x4 acc[2][4];
#pragma unroll
    for (int rt = 0; rt < 2; rt++)
#pragma unroll
        for (int ct = 0; ct < 4; ct++) acc[rt][ct] = (f32x4){0.f, 0.f, 0.f, 0.f};
    {
        const unsigned short* wb = (const unsigned short*)(ws + OFF_WMB) + (size_t)b * 32768u;
#pragma unroll
        for (int kk = 0; kk < 4; kk++) {
            int ko = kk * 32 + lk * 8;
            bf16x8 a[2];
#pragma unroll
            for (int rt = 0; rt < 2; rt++)
                a[rt] = *(const bf16x8*)(xs + (rt * 16 + lrow) * LDP + ko);
            bf16x8 bf[4];
#pragma unroll
            for (int ct = 0; ct < 4; ct++)
                bf[ct] = *(const bf16x8*)(wb + (size_t)(colbase + ct * 16 + lrow) * DIN + ko);
#pragma unroll
            for (int rt = 0; rt < 2; rt++)
#pragma unroll
                for (int ct = 0; ct < 4; ct++)
                    acc[rt][ct] = __builtin_amdgcn_mfma_f32_16x16x32_bf16(a[rt], bf[ct], acc[rt][ct], 0, 0, 0);
        }
#pragma unroll
        for (int ct = 0; ct < 4; ct++) {
            float bv = ws[OFF_TB + b * DOUT + colbase + ct * 16 + lrow];
#pragma unroll
            for (int rt = 0; rt < 2; rt++)
#pragma unroll
                for (int r = 0; r < 4; r++) acc[rt][ct][r] += bv;
        }
    }

    // ---- pass 0: x1 = x @ Wl^T + bl -> registers ----
    f32x4 acc0[2][4];
#pragma unroll
    for (int rt = 0; rt < 2; rt++)
#pragma unroll
        for (int ct = 0; ct < 4; ct++) acc0[rt][ct] = (f32x4){0.f, 0.f, 0.f, 0.f};
    {
        const unsigned short* wb = (const unsigned short*)(ws + OFF_WLB);
#pragma unroll
        for (int kk = 0; kk < 4; kk++) {
            int ko = kk * 32 + lk * 8;
            bf16x8 a[2];
#pragma unroll
            for (int rt = 0; rt < 2; rt++)
                a[rt] = *(const bf16x8*)(xs + (rt * 16 + lrow) * LDP + ko);
            bf16x8 bf[4];
#pragma unroll
            for (int ct = 0; ct < 4; ct++)
                bf[ct] = *(const bf16x8*)(wb + (size_t)(colbase + ct * 16 + lrow) * DIN + ko);
#pragma unroll
            for (int rt = 0; rt < 2; rt++)
#pragma unroll
                for (int ct = 0; ct < 4; ct++)
                    acc0[rt][ct] = __builtin_amdgcn_mfma_f32_16x16x32_bf16(a[rt], bf[ct], acc0[rt][ct], 0, 0, 0);
        }
#pragma unroll
        for (int ct = 0; ct < 4; ct++) {
            float bv = bl[colbase + ct * 16 + lrow];
#pragma unroll
            for (int rt = 0; rt < 2; rt++)
#pragma unroll
                for (int r = 0; r < 4; r++) acc0[rt][ct][r] += bv;
        }
    }

    // ---- epilogue straight from registers: out = (x1 + relu(bn(tt)))*g + hb ----
    float gv[4], hbv[4];
#pragma unroll
    for (int ct = 0; ct < 4; ct++) {
        int o = colbase + ct * 16 + lrow;
        gv[ct]  = ws[OFF_G  + b * DOUT + o];
        hbv[ct] = ws[OFF_HB + b * DOUT + o];
    }
#pragma unroll
    for (int rt = 0; rt < 2; rt++)
#pragma unroll
        for (int r = 0; r < 4; r++) {
            int nidx = rt * 16 + lk * 4 + r;
            float sc = scs[nidx], sh = shs[nidx];
            int n = n0 + nidx;
#pragma unroll
            for (int ct = 0; ct < 4; ct++) {
                int o = colbase + ct * 16 + lrow;
                float rv = fmaxf(acc[rt][ct][r] * sc + sh, 0.f);
                out[(size_t)((b * NN + n) * DOUT) + o] = (acc0[rt][ct][r] + rv) * gv[ct] + hbv[ct];
            }
        }
}

extern "C" void kernel_launch(void* const* d_in, const int* in_sizes, int n_in,
                              void* d_out, int out_size, void* d_ws, size_t ws_size,
                              hipStream_t stream) {
    const float* ctx   = (const float*)d_in[0];
    const float* x     = (const float*)d_in[1];
    const float* Wl    = (const float*)d_in[2];
    const float* bl    = (const float*)d_in[3];
    const float* Whb   = (const float*)d_in[4];
    const float* Wg    = (const float*)d_in[5];
    const float* bg    = (const float*)d_in[6];
    const float* Wk    = (const float*)d_in[7];
    const float* Wv    = (const float*)d_in[8];
    const float* Wtc   = (const float*)d_in[9];
    const float* btc   = (const float*)d_in[10];
    const float* gamma = (const float*)d_in[11];
    const float* beta  = (const float*)d_in[12];
    float* out = (float*)d_out;
    float* ws  = (float*)d_ws;

    kXW <<<44, 256, 0, stream>>>(Wl, Wtc, Wk, Wv, Wg, Whb, ws);
    kP  <<<BB, 1024, 0, stream>>>(ctx, bg, ws);
    k45 <<<dim3(2, BB), 512, 0, stream>>>(bl, btc, ws);
    kS  <<<dim3(BB, 32), 256, 0, stream>>>(x, ws);
    kBN <<<8, 256, 0, stream>>>(gamma, beta, ws);
    kF  <<<dim3(BB, 64), 256, 0, stream>>>(x, bl, out, ws);
}